// Round 9
// baseline (519.362 us; speedup 1.0000x reference)
//
#include <hip/hip_runtime.h>
#include <math.h>

#define BLK 256
#define BKT_BITS 9          // 512 nodes per scan block
#define BKT (1<<BKT_BITS)

typedef __attribute__((ext_vector_type(8))) short bf16x8;
typedef __attribute__((ext_vector_type(4))) float f32x4;

__device__ inline unsigned short f2b(float f){
  union { float f; unsigned int u; } v; v.f = f;
  unsigned int u = v.u;
  return (unsigned short)((u + 0x7FFF + ((u >> 16) & 1)) >> 16);
}
__device__ inline float b2f_lo(unsigned int u){
  union { unsigned int u; float f; } v; v.u = u << 16; return v.f;
}
__device__ inline float b2f_hi(unsigned int u){
  union { unsigned int u; float f; } v; v.u = u & 0xFFFF0000u; return v.f;
}
// packed 2xbf16 convert (RNE, same rounding as f2b) — 1 instr per 2 floats
__device__ inline unsigned pkbf(float lo, float hi){
  unsigned r;
  asm("v_cvt_pk_bf16_f32 %0, %1, %2" : "=v"(r) : "v"(lo), "v"(hi));
  return r;
}

// ---------------- CSR build v3: global-atomic, 3 kernels ----------------
// Replaces the LDS bucket-sort (binC+bfill): LDS atomic storms with 16-42-way
// same-address contention were ~110us; global atomics to 100K DISTINCT addresses
// (16 collisions/address over the kernel lifetime, spread across L2 slices) are cheap.

// degree histogram (fire-and-forget global atomics) + W1 transpose/cvt tail
__global__ __launch_bounds__(256)
void deg_w1t(const int* __restrict__ dst, int* __restrict__ deg,
             const float* __restrict__ W1, unsigned short* __restrict__ W1T,
             int E, int NQB){
  int b = blockIdx.x;
  if (b >= NQB){   // W1 transpose+cvt tail
    int t2 = (b - NQB)*256 + threadIdx.x;
    if (t2 < 256*128){
      int k = t2 >> 7, n = t2 & 127;
      W1T[n*256 + k] = f2b(W1[t2]);
    }
    return;
  }
  int idx = (b*256 + threadIdx.x)*4;
  if (idx < E){
    int4 d = *(const int4*)(dst + idx);
    atomicAdd(&deg[d.x],1);
    atomicAdd(&deg[d.y],1);
    atomicAdd(&deg[d.z],1);
    atomicAdd(&deg[d.w],1);
  }
}

// per-512-node block: prefix over deg[0..base) (L2-hot strided reads + LDS reduce),
// local 256-scan of (deg+1), emit rowptr / wcur(copy) / dinv / self-loop col slot.
__global__ __launch_bounds__(256)
void scan_k(const int* __restrict__ deg, int* __restrict__ rowptr,
            int* __restrict__ wcur, float* __restrict__ dinv,
            int* __restrict__ col, int N){
  __shared__ int sscan[256];
  __shared__ int sboff;
  int b = blockIdx.x;
  int t = threadIdx.x;
  if (t==0) sboff = 0;
  __syncthreads();
  int base = b << BKT_BITS;
  int partial = 0;
  for (int j=t; j<base; j+=256) partial += deg[j];
  if (partial) atomicAdd(&sboff, partial);
  __syncthreads();
  int i0 = base + 2*t, i1 = base + 2*t + 1;
  int d0 = (i0 < N) ? deg[i0] : 0;
  int d1 = (i1 < N) ? deg[i1] : 0;
  int n0 = (i0 < N) ? d0+1 : 0;
  int n1 = (i1 < N) ? d1+1 : 0;
  int tsum = n0+n1;
  sscan[t] = tsum; __syncthreads();
  for (int off=1; off<256; off<<=1){
    int v = (t>=off)? sscan[t-off]:0;
    __syncthreads();
    sscan[t]+=v;
    __syncthreads();
  }
  int run = sscan[t]-tsum;
  int gbase = sboff + base;   // prior edges + prior self-loops
  int rp0 = gbase + run, rp1 = rp0 + n0;
  if (i0 < N){
    rowptr[i0] = rp0; wcur[i0] = rp0;
    dinv[i0] = rsqrtf((float)(d0+1));
    col[rp0 + d0] = i0;                 // self-loop in last slot
    if (i0 == N-1) rowptr[N] = rp0 + d0 + 1;
  }
  if (i1 < N){
    rowptr[i1] = rp1; wcur[i1] = rp1;
    dinv[i1] = rsqrtf((float)(d1+1));
    col[rp1 + d1] = i1;
    if (i1 == N-1) rowptr[N] = rp1 + d1 + 1;
  }
}

// edge fill: slot reservation via returning global atomic, scattered 4B col writes.
__global__ __launch_bounds__(256)
void fill_k(const int* __restrict__ src, const int* __restrict__ dst,
            int* __restrict__ wcur, int* __restrict__ col, int E){
  int idx = (blockIdx.x*256 + threadIdx.x)*4;
  if (idx < E){
    int4 s4 = *(const int4*)(src + idx);
    int4 d4 = *(const int4*)(dst + idx);
    int p0 = atomicAdd(&wcur[d4.x],1);
    int p1 = atomicAdd(&wcur[d4.y],1);
    int p2 = atomicAdd(&wcur[d4.z],1);
    int p3 = atomicAdd(&wcur[d4.w],1);
    col[p0] = s4.x; col[p1] = s4.y; col[p2] = s4.z; col[p3] = s4.w;
  }
}

// ---------------- GEMM1 (MFMA bf16): h1b[r] = dinv[r] * (x @ W1)[r], bf16 ----------------
// v4: W-stationary barrier-free structure, 512-thread blocks (8 waves x 32 rows
// = 256 rows/block). Depth-2 reg prefetch, cvt_pk bf16.

__global__ __launch_bounds__(512)
void gemm1_mfma(const float* __restrict__ X, const unsigned short* __restrict__ W1T,
                const float* __restrict__ dinv, unsigned short* __restrict__ H1B, int M){
  // 64 B-fragments: frag f = (ct = f>>3, kstep = f&7); per-lane 16B at f*512(shorts)+lane*8
  __shared__ __attribute__((aligned(16))) unsigned short wsh[64*512];
  const int tid = threadIdx.x;
  const int wave = tid >> 6, lane = tid & 63;
  const int quad = lane >> 4, l16 = lane & 15;

  // ---- stage W1T -> swizzled LDS frags (one time, 8 uint4 per thread) ----
  #pragma unroll
  for (int f0=0; f0<64; f0+=8){
    int f = f0 + wave;
    int ct = f >> 3, ts = f & 7;
    uint4 v = *(const uint4*)(W1T + (ct*16 + l16)*256 + ts*32 + quad*8);
    *(uint4*)(wsh + f*512 + lane*8) = v;
  }
  __syncthreads();

  const int row0 = blockIdx.x * 256 + wave * 32;
  int rA = row0 + l16;
  int rB = rA + 16;
  int rAc = (rA < M) ? rA : (M-1);
  int rBc = (rB < M) ? rB : (M-1);
  const float* xA = X + (size_t)rAc*256 + quad*8;
  const float* xB = X + (size_t)rBc*256 + quad*8;

  f32x4 acc[2][8];
  #pragma unroll
  for (int i=0;i<2;i++)
    #pragma unroll
    for (int j=0;j<8;j++) acc[i][j] = (f32x4){0.f,0.f,0.f,0.f};

  // depth-2 register prefetch of A fragments (2 rows x 32B per step)
  float4 pf[2][4];
  #pragma unroll
  for (int s=0;s<2;s++){
    pf[s][0] = *(const float4*)(xA + s*32);
    pf[s][1] = *(const float4*)(xA + s*32 + 4);
    pf[s][2] = *(const float4*)(xB + s*32);
    pf[s][3] = *(const float4*)(xB + s*32 + 4);
  }

  #pragma unroll
  for (int t=0; t<8; t++){
    const int cur = t & 1;
    union { bf16x8 v; unsigned u[4]; } fa, fb;
    fa.u[0] = pkbf(pf[cur][0].x, pf[cur][0].y);
    fa.u[1] = pkbf(pf[cur][0].z, pf[cur][0].w);
    fa.u[2] = pkbf(pf[cur][1].x, pf[cur][1].y);
    fa.u[3] = pkbf(pf[cur][1].z, pf[cur][1].w);
    fb.u[0] = pkbf(pf[cur][2].x, pf[cur][2].y);
    fb.u[1] = pkbf(pf[cur][2].z, pf[cur][2].w);
    fb.u[2] = pkbf(pf[cur][3].x, pf[cur][3].y);
    fb.u[3] = pkbf(pf[cur][3].z, pf[cur][3].w);
    if (t < 6){
      pf[cur][0] = *(const float4*)(xA + (t+2)*32);
      pf[cur][1] = *(const float4*)(xA + (t+2)*32 + 4);
      pf[cur][2] = *(const float4*)(xB + (t+2)*32);
      pf[cur][3] = *(const float4*)(xB + (t+2)*32 + 4);
    }
    #pragma unroll
    for (int ct=0; ct<8; ct++){
      bf16x8 bf = *(const bf16x8*)(wsh + (ct*8 + t)*512 + lane*8);
      acc[0][ct] = __builtin_amdgcn_mfma_f32_16x16x32_bf16(fa.v, bf, acc[0][ct], 0, 0, 0);
      acc[1][ct] = __builtin_amdgcn_mfma_f32_16x16x32_bf16(fb.v, bf, acc[1][ct], 0, 0, 0);
    }
  }

  #pragma unroll
  for (int rt=0; rt<2; rt++){
    int rbase = row0 + rt*16 + quad*4;
    #pragma unroll
    for (int rg=0; rg<4; rg++){
      int grow = rbase + rg;
      if (grow < M){
        float dv = dinv[grow];
        #pragma unroll
        for (int ct=0; ct<8; ct++)
          H1B[(size_t)grow*128 + ct*16 + l16] = f2b(dv * acc[rt][ct][rg]);
      }
    }
  }
}

// ---------------- agg1: wave/node gather, 4 edge-groups x 16 lanes x 16B ----------------

__device__ inline void acc8(float* a, uint4 u){
  a[0]+=b2f_lo(u.x); a[1]+=b2f_hi(u.x); a[2]+=b2f_lo(u.y); a[3]+=b2f_hi(u.y);
  a[4]+=b2f_lo(u.z); a[5]+=b2f_hi(u.z); a[6]+=b2f_lo(u.w); a[7]+=b2f_hi(u.w);
}

__global__ __launch_bounds__(256)
void agg1_kernel(const unsigned short* __restrict__ H1B, const int* __restrict__ rowptr,
                 const int* __restrict__ col, const float* __restrict__ dinv,
                 const float* __restrict__ b1, unsigned int* __restrict__ R1B, int N){
  int node = blockIdx.x * 4 + (threadIdx.x >> 6);
  int lane = threadIdx.x & 63;
  int g   = lane >> 4;    // edge sub-group 0..3
  int l16 = lane & 15;    // 16B chunk within the 256B row
  if (node >= N) return;
  int s = rowptr[node], e = rowptr[node+1];
  float a[8];
  #pragma unroll
  for (int k=0;k<8;k++) a[k]=0.f;
  const char* hbase = (const char*)H1B + l16*16;
  int j = s;
  for (; j+15 < e; j+=16){
    int c0 = col[j+g], c1 = col[j+4+g], c2 = col[j+8+g], c3 = col[j+12+g];
    uint4 u0 = *(const uint4*)(hbase + (((unsigned)c0) << 8));
    uint4 u1 = *(const uint4*)(hbase + (((unsigned)c1) << 8));
    uint4 u2 = *(const uint4*)(hbase + (((unsigned)c2) << 8));
    uint4 u3 = *(const uint4*)(hbase + (((unsigned)c3) << 8));
    acc8(a, u0); acc8(a, u1); acc8(a, u2); acc8(a, u3);
  }
  for (; j+7 < e; j+=8){
    int c0 = col[j+g], c1 = col[j+4+g];
    uint4 u0 = *(const uint4*)(hbase + (((unsigned)c0) << 8));
    uint4 u1 = *(const uint4*)(hbase + (((unsigned)c1) << 8));
    acc8(a, u0); acc8(a, u1);
  }
  {
    int rem = e - j;   // 0..7
    if (g < rem){
      int c0 = col[j+g];
      uint4 u0 = *(const uint4*)(hbase + (((unsigned)c0) << 8));
      acc8(a, u0);
    }
    if (g+4 < rem){
      int c1 = col[j+4+g];
      uint4 u1 = *(const uint4*)(hbase + (((unsigned)c1) << 8));
      acc8(a, u1);
    }
  }
  #pragma unroll
  for (int k=0;k<8;k++){
    a[k] += __shfl_xor(a[k], 16);
    a[k] += __shfl_xor(a[k], 32);
  }
  if (g == 0){
    float dv = dinv[node];
    float4 bl = *(const float4*)(b1 + l16*8);
    float4 bh = *(const float4*)(b1 + l16*8 + 4);
    float f0, f1;
    unsigned int o0, o1, o2, o3;
    f0 = fmaxf(dv*a[0] + bl.x, 0.f); f1 = fmaxf(dv*a[1] + bl.y, 0.f);
    o0 = (unsigned)f2b(f0) | ((unsigned)f2b(f1) << 16);
    f0 = fmaxf(dv*a[2] + bl.z, 0.f); f1 = fmaxf(dv*a[3] + bl.w, 0.f);
    o1 = (unsigned)f2b(f0) | ((unsigned)f2b(f1) << 16);
    f0 = fmaxf(dv*a[4] + bh.x, 0.f); f1 = fmaxf(dv*a[5] + bh.y, 0.f);
    o2 = (unsigned)f2b(f0) | ((unsigned)f2b(f1) << 16);
    f0 = fmaxf(dv*a[6] + bh.z, 0.f); f1 = fmaxf(dv*a[7] + bh.w, 0.f);
    o3 = (unsigned)f2b(f0) | ((unsigned)f2b(f1) << 16);
    *(uint4*)(R1B + (size_t)node*64 + l16*4) = make_uint4(o0, o1, o2, o3);
  }
}

// ---------------- GEMM2: h2b[r] = bf16( dinv[r] * (r1[r] @ W2) ), packed 32B stride ----------------
// padding dwords [5..7] zeroed so agg2's wide 8-dword row loads read zeros.

__global__ __launch_bounds__(256)
void gemm2_kernel(const unsigned int* __restrict__ R1B, const float* __restrict__ W2,
                  const float* __restrict__ dinv, unsigned int* __restrict__ H2B, int M){
  __shared__ float w2s[128*10];
  for (int i = threadIdx.x; i < 128*10; i += blockDim.x) w2s[i] = W2[i];
  __syncthreads();
  int r = blockIdx.x*blockDim.x + threadIdx.x;
  if (r >= M) return;
  float acc[10];
  #pragma unroll
  for (int c=0;c<10;c++) acc[c] = 0.f;
  const unsigned int* row = R1B + (size_t)r*64;
  for (int k=0;k<64;k+=4){
    uint4 u = *(const uint4*)(row + k);
    float f0 = b2f_lo(u.x), f1 = b2f_hi(u.x);
    float f2 = b2f_lo(u.y), f3 = b2f_hi(u.y);
    float f4 = b2f_lo(u.z), f5 = b2f_hi(u.z);
    float f6 = b2f_lo(u.w), f7 = b2f_hi(u.w);
    #pragma unroll
    for (int c=0;c<10;c++){
      acc[c] += f0*w2s[(2*k+0)*10+c] + f1*w2s[(2*k+1)*10+c]
              + f2*w2s[(2*k+2)*10+c] + f3*w2s[(2*k+3)*10+c]
              + f4*w2s[(2*k+4)*10+c] + f5*w2s[(2*k+5)*10+c]
              + f6*w2s[(2*k+6)*10+c] + f7*w2s[(2*k+7)*10+c];
    }
  }
  float dv = dinv[r];
  unsigned int p[5];
  #pragma unroll
  for (int c=0;c<5;c++)
    p[c] = (unsigned)f2b(dv*acc[2*c]) | ((unsigned)f2b(dv*acc[2*c+1]) << 16);
  unsigned int* op = H2B + (size_t)r*8;
  *(uint4*)op = make_uint4(p[0],p[1],p[2],p[3]);
  *(uint4*)(op+4) = make_uint4(p[4],0u,0u,0u);
}

// ---------------- agg2 + bias + log_softmax: 16 lanes/node wide gather ----------------

__global__ __launch_bounds__(256)
void agg2_softmax_kernel(const unsigned int* __restrict__ H2B, const int* __restrict__ rowptr,
                         const int* __restrict__ col, const float* __restrict__ dinv,
                         const float* __restrict__ b2, float* __restrict__ out, int N){
  int tid = threadIdx.x;
  int node = blockIdx.x * 16 + (tid >> 4);
  int l16 = tid & 15;
  int g2 = l16 >> 3;      // edge sub-group 0..1
  int l8 = l16 & 7;       // dword slot within 32B row
  if (node >= N) return;
  int s = rowptr[node], e = rowptr[node+1];
  float aLo = 0.f, aHi = 0.f, bLo = 0.f, bHi = 0.f;
  const unsigned int* hb = H2B + l8;
  int j = s;
  for (; j+3 < e; j += 4){
    unsigned u0 = hb[(size_t)col[j+g2]*8];
    unsigned u1 = hb[(size_t)col[j+2+g2]*8];
    aLo += b2f_lo(u0); aHi += b2f_hi(u0);
    bLo += b2f_lo(u1); bHi += b2f_hi(u1);
  }
  for (; j+1 < e; j += 2){
    unsigned u0 = hb[(size_t)col[j+g2]*8];
    aLo += b2f_lo(u0); aHi += b2f_hi(u0);
  }
  if (j < e && g2 == 0){
    unsigned u0 = hb[(size_t)col[j]*8];
    aLo += b2f_lo(u0); aHi += b2f_hi(u0);
  }
  aLo += bLo; aHi += bHi;
  aLo += __shfl_xor(aLo, 8);
  aHi += __shfl_xor(aHi, 8);
  float dv = dinv[node];
  float2 bb = (l8 < 5) ? *(const float2*)(b2 + 2*l8) : make_float2(0.f, 0.f);
  float c0 = (l8 < 5) ? (dv*aLo + bb.x) : -1e30f;
  float c1 = (l8 < 5) ? (dv*aHi + bb.y) : -1e30f;
  float m = fmaxf(c0, c1);
  m = fmaxf(m, __shfl_xor(m, 1));
  m = fmaxf(m, __shfl_xor(m, 2));
  m = fmaxf(m, __shfl_xor(m, 4));
  float ex = (l8 < 5) ? (expf(c0 - m) + expf(c1 - m)) : 0.f;
  ex += __shfl_xor(ex, 1);
  ex += __shfl_xor(ex, 2);
  ex += __shfl_xor(ex, 4);
  float lg = m + logf(ex);
  if (l8 < 5 && g2 == 0)
    *(float2*)(out + (size_t)node*10 + 2*l8) = make_float2(c0 - lg, c1 - lg);
}

// ---------------- launch ----------------

extern "C" void kernel_launch(void* const* d_in, const int* in_sizes, int n_in,
                              void* d_out, int out_size, void* d_ws, size_t ws_size,
                              hipStream_t stream){
  const float* x    = (const float*)d_in[0];
  const int*   ei   = (const int*)d_in[1];
  const float* W1   = (const float*)d_in[2];
  const float* b1   = (const float*)d_in[3];
  const float* W2   = (const float*)d_in[4];
  const float* b2   = (const float*)d_in[5];
  float* out = (float*)d_out;

  const int N = in_sizes[0] / 256;   // 100000
  const int E = in_sizes[1] / 2;     // 1600000
  const int NNZ = E + N;
  const int* src = ei;
  const int* dst = ei + E;
  const int NB = (N + BKT - 1) >> BKT_BITS;   // 196 scan blocks
  const int WB = 128;                         // wcvt tail blocks

  char* ws = (char*)d_ws;
  size_t off = 0;
  auto alloc = [&](size_t bytes)->char*{
    char* p = ws + off;
    off = (off + bytes + 255) & ~(size_t)255;
    return p;
  };
  int*   deg    = (int*)  alloc((size_t)N*4);   // zeroed each launch
  int*   wcur   = (int*)  alloc((size_t)N*4);
  float* dinv   = (float*)alloc((size_t)N*4);
  int*   rowptr = (int*)  alloc((size_t)(N+1)*4);
  int*   col    = (int*)  alloc((size_t)NNZ*4);
  unsigned short* w1t = (unsigned short*)alloc((size_t)128*256*2);
  unsigned short* h1b = (unsigned short*)alloc((size_t)N*128*2);
  unsigned int*   r1b = (unsigned int*)  alloc((size_t)N*64*4);
  unsigned int*   h2b = (unsigned int*)  alloc((size_t)N*8*4);
  (void)ws_size;

  hipMemsetAsync(deg, 0, (size_t)N*4, stream);

  const int NQB = (E/4 + 255) / 256;   // 1563 quad-blocks

  deg_w1t<<<NQB + WB, 256, 0, stream>>>(dst, deg, W1, w1t, E, NQB);
  scan_k<<<NB, 256, 0, stream>>>(deg, rowptr, wcur, dinv, col, N);
  fill_k<<<NQB, 256, 0, stream>>>(src, dst, wcur, col, E);

  gemm1_mfma<<<(N+255)/256, 512, 0, stream>>>(x, w1t, dinv, h1b, N);
  agg1_kernel<<<(N+3)/4, 256, 0, stream>>>(h1b, rowptr, col, dinv, b1, r1b, N);
  gemm2_kernel<<<(N+BLK-1)/BLK, BLK, 0, stream>>>(r1b, W2, dinv, h2b, N);
  agg2_softmax_kernel<<<(N+15)/16, BLK, 0, stream>>>(h2b, rowptr, col, dinv, b2, out, N);
}

// Round 10
// 322.243 us; speedup vs baseline: 1.6117x; 1.6117x over previous
//
#include <hip/hip_runtime.h>
#include <math.h>

#define BLK 256
// bucketed CSR build: 256 dst-nodes per bucket (small buckets -> big grids)
#define BKT_BITS 8
#define BKT (1<<BKT_BITS)
#define NBMAX 512
#define EB 2048       // edges per bin-block (782 blocks -> ~3/CU)
#define BSTRIDE 8192  // per-bucket slot stride in bins (mean fill 4092, 64-sigma safe)

typedef __attribute__((ext_vector_type(8))) short bf16x8;
typedef __attribute__((ext_vector_type(4))) float f32x4;

__device__ inline unsigned short f2b(float f){
  union { float f; unsigned int u; } v; v.f = f;
  unsigned int u = v.u;
  return (unsigned short)((u + 0x7FFF + ((u >> 16) & 1)) >> 16);
}
__device__ inline float b2f_lo(unsigned int u){
  union { unsigned int u; float f; } v; v.u = u << 16; return v.f;
}
__device__ inline float b2f_hi(unsigned int u){
  union { unsigned int u; float f; } v; v.u = u & 0xFFFF0000u; return v.f;
}
// packed 2xbf16 convert (RNE, same rounding as f2b) — 1 instr per 2 floats
__device__ inline unsigned pkbf(float lo, float hi){
  unsigned r;
  asm("v_cvt_pk_bf16_f32 %0, %1, %2" : "=v"(r) : "v"(lo), "v"(hi));
  return r;
}

// ---------------- CSR build: LDS bucket sort, high-parallelism variant ----------------
// R9 lesson: scattered 4B global writes = 16x write amplification (106MB for 6.4MB of col,
// 133us). The LDS sort exists to make col writes dense. R7's cost was GRID STARVATION
// (196 blocks on 256 CUs), not LDS atomics: EB 8192->2048 and BKT 512->256 give
// 782/391-block grids with identical total work.

// bin edges into fixed-stride bucket regions; bcnt doubles as reservation + final count.
__global__ __launch_bounds__(256)
void binC(const int* __restrict__ src, const int* __restrict__ dst,
          int* __restrict__ bcnt, unsigned int* __restrict__ bins, int E, int NB){
  __shared__ int lh[NBMAX];
  __shared__ int lofs[NBMAX];
  __shared__ int lcur[NBMAX];
  __shared__ int gres[NBMAX];
  __shared__ int sscan[256];
  __shared__ __attribute__((aligned(16))) int2 buf[EB];
  int t = threadIdx.x;
  lh[t] = 0; lh[t+256] = 0;
  __syncthreads();
  int base = blockIdx.x*EB;
  // histogram: int4 edge loads (E % 4 == 0)
  #pragma unroll
  for (int k=0;k<EB/1024;k++){
    int idx = base + (k*256 + t)*4;
    if (idx < E){
      int4 d = *(const int4*)(dst + idx);
      atomicAdd(&lh[d.x>>BKT_BITS],1);
      atomicAdd(&lh[d.y>>BKT_BITS],1);
      atomicAdd(&lh[d.z>>BKT_BITS],1);
      atomicAdd(&lh[d.w>>BKT_BITS],1);
    }
  }
  __syncthreads();
  // exclusive scan of lh[0..512) (2 entries/thread)
  int i0 = 2*t, i1 = 2*t+1;
  int v0 = lh[i0], v1 = lh[i1];
  int tsum = v0+v1;
  sscan[t] = tsum; __syncthreads();
  for (int off=1; off<256; off<<=1){
    int v = (t>=off)? sscan[t-off]:0;
    __syncthreads();
    sscan[t]+=v;
    __syncthreads();
  }
  int run = sscan[t]-tsum;
  lofs[i0] = run;      lofs[i1] = run+v0;
  lcur[i0] = run;      lcur[i1] = run+v0;
  // reserve per-bucket global space
  for (int i=t;i<NBMAX;i+=256)
    gres[i] = lh[i] ? (i*BSTRIDE + atomicAdd(&bcnt[i], lh[i])) : 0;
  __syncthreads();
  // scatter into LDS buf grouped by bucket
  #pragma unroll
  for (int k=0;k<EB/1024;k++){
    int idx = base + (k*256 + t)*4;
    if (idx < E){
      int4 s4 = *(const int4*)(src + idx);
      int4 d4 = *(const int4*)(dst + idx);
      int p;
      p = atomicAdd(&lcur[d4.x>>BKT_BITS],1); buf[p] = make_int2(s4.x,d4.x);
      p = atomicAdd(&lcur[d4.y>>BKT_BITS],1); buf[p] = make_int2(s4.y,d4.y);
      p = atomicAdd(&lcur[d4.z>>BKT_BITS],1); buf[p] = make_int2(s4.z,d4.z);
      p = atomicAdd(&lcur[d4.w>>BKT_BITS],1); buf[p] = make_int2(s4.w,d4.w);
    }
  }
  __syncthreads();
  // dense packed writeout: src<<8 | dst&255 (17+8 = 25 bits)
  int total = E - base; if (total > EB) total = EB;
  for (int i=t; i<total; i+=256){
    int2 pr = buf[i];
    int b = pr.y>>BKT_BITS;
    bins[gres[b] + (i - lofs[b])] = ((unsigned)pr.x << BKT_BITS) | (unsigned)(pr.y & (BKT-1));
  }
}

// per-bucket (256 nodes): degree -> 256-scan -> rowptr/dinv/self-loop -> col fill.
// W1 transpose/cvt as independent tail blocks.
__global__ __launch_bounds__(256)
void bfill_all(const unsigned int* __restrict__ bins, const int* __restrict__ bcnt,
               int* __restrict__ rowptr, float* __restrict__ dinv, int* __restrict__ col,
               const float* __restrict__ W1, unsigned short* __restrict__ W1T,
               int N, int NB){
  int b = blockIdx.x;
  if (b >= NB){   // W1 transpose+cvt tail
    int t2 = (b - NB)*256 + threadIdx.x;
    if (t2 < 256*128){
      int k = t2 >> 7, n = t2 & 127;
      W1T[n*256 + k] = f2b(W1[t2]);
    }
    return;
  }
  __shared__ int dcnt[BKT];
  __shared__ int rp[BKT];
  __shared__ int cur[BKT];
  __shared__ int sscan[256];
  __shared__ int sboff;
  int t = threadIdx.x;
  if (t==0) sboff = 0;
  dcnt[t] = 0;
  __syncthreads();
  // bucket edge base = sum bcnt[0..b)
  int partial = 0;
  for (int j=t; j<b; j+=256) partial += bcnt[j];
  if (partial) atomicAdd(&sboff, partial);
  __syncthreads();
  int s = sboff, cnt = bcnt[b];
  const unsigned int* mybins = bins + (size_t)b*BSTRIDE;
  // degree count
  for (int i=t;i<cnt;i+=256) atomicAdd(&dcnt[mybins[i] & (BKT-1)], 1);
  __syncthreads();
  // exclusive 256-scan of (deg+1), 1 node/thread
  int base = b<<BKT_BITS;
  int node = base + t;
  int d0 = dcnt[t];
  int n0 = (node < N) ? d0+1 : 0;
  sscan[t] = n0; __syncthreads();
  for (int off=1; off<256; off<<=1){
    int v = (t>=off)? sscan[t-off]:0;
    __syncthreads();
    sscan[t]+=v;
    __syncthreads();
  }
  int run = sscan[t]-n0;
  int rp0 = s + base + run;   // prior buckets: s edges + base self-loops
  rp[t] = rp0; cur[t] = 0;
  if (node < N){
    rowptr[node] = rp0;
    dinv[node] = rsqrtf((float)(d0+1));
    col[rp0 + d0] = node;               // self-loop last (slot disjoint from fill)
    if (node == N-1) rowptr[N] = rp0 + d0 + 1;
  }
  __syncthreads();
  // fill col via LDS cursors (dense per-bucket writes)
  for (int i=t;i<cnt;i+=256){
    unsigned pk = mybins[i];
    int ln = pk & (BKT-1);
    int slot = atomicAdd(&cur[ln], 1);
    col[rp[ln] + slot] = (int)(pk >> BKT_BITS);
  }
}

// ---------------- GEMM1 (MFMA bf16): h1b[r] = dinv[r] * (x @ W1)[r], bf16 ----------------
// v4: W-stationary barrier-free structure, 512-thread blocks (8 waves x 32 rows
// = 256 rows/block). Depth-2 reg prefetch, cvt_pk bf16.

__global__ __launch_bounds__(512)
void gemm1_mfma(const float* __restrict__ X, const unsigned short* __restrict__ W1T,
                const float* __restrict__ dinv, unsigned short* __restrict__ H1B, int M){
  // 64 B-fragments: frag f = (ct = f>>3, kstep = f&7); per-lane 16B at f*512(shorts)+lane*8
  __shared__ __attribute__((aligned(16))) unsigned short wsh[64*512];
  const int tid = threadIdx.x;
  const int wave = tid >> 6, lane = tid & 63;
  const int quad = lane >> 4, l16 = lane & 15;

  #pragma unroll
  for (int f0=0; f0<64; f0+=8){
    int f = f0 + wave;
    int ct = f >> 3, ts = f & 7;
    uint4 v = *(const uint4*)(W1T + (ct*16 + l16)*256 + ts*32 + quad*8);
    *(uint4*)(wsh + f*512 + lane*8) = v;
  }
  __syncthreads();

  const int row0 = blockIdx.x * 256 + wave * 32;
  int rA = row0 + l16;
  int rB = rA + 16;
  int rAc = (rA < M) ? rA : (M-1);
  int rBc = (rB < M) ? rB : (M-1);
  const float* xA = X + (size_t)rAc*256 + quad*8;
  const float* xB = X + (size_t)rBc*256 + quad*8;

  f32x4 acc[2][8];
  #pragma unroll
  for (int i=0;i<2;i++)
    #pragma unroll
    for (int j=0;j<8;j++) acc[i][j] = (f32x4){0.f,0.f,0.f,0.f};

  float4 pf[2][4];
  #pragma unroll
  for (int s=0;s<2;s++){
    pf[s][0] = *(const float4*)(xA + s*32);
    pf[s][1] = *(const float4*)(xA + s*32 + 4);
    pf[s][2] = *(const float4*)(xB + s*32);
    pf[s][3] = *(const float4*)(xB + s*32 + 4);
  }

  #pragma unroll
  for (int t=0; t<8; t++){
    const int cur = t & 1;
    union { bf16x8 v; unsigned u[4]; } fa, fb;
    fa.u[0] = pkbf(pf[cur][0].x, pf[cur][0].y);
    fa.u[1] = pkbf(pf[cur][0].z, pf[cur][0].w);
    fa.u[2] = pkbf(pf[cur][1].x, pf[cur][1].y);
    fa.u[3] = pkbf(pf[cur][1].z, pf[cur][1].w);
    fb.u[0] = pkbf(pf[cur][2].x, pf[cur][2].y);
    fb.u[1] = pkbf(pf[cur][2].z, pf[cur][2].w);
    fb.u[2] = pkbf(pf[cur][3].x, pf[cur][3].y);
    fb.u[3] = pkbf(pf[cur][3].z, pf[cur][3].w);
    if (t < 6){
      pf[cur][0] = *(const float4*)(xA + (t+2)*32);
      pf[cur][1] = *(const float4*)(xA + (t+2)*32 + 4);
      pf[cur][2] = *(const float4*)(xB + (t+2)*32);
      pf[cur][3] = *(const float4*)(xB + (t+2)*32 + 4);
    }
    #pragma unroll
    for (int ct=0; ct<8; ct++){
      bf16x8 bf = *(const bf16x8*)(wsh + (ct*8 + t)*512 + lane*8);
      acc[0][ct] = __builtin_amdgcn_mfma_f32_16x16x32_bf16(fa.v, bf, acc[0][ct], 0, 0, 0);
      acc[1][ct] = __builtin_amdgcn_mfma_f32_16x16x32_bf16(fb.v, bf, acc[1][ct], 0, 0, 0);
    }
  }

  #pragma unroll
  for (int rt=0; rt<2; rt++){
    int rbase = row0 + rt*16 + quad*4;
    #pragma unroll
    for (int rg=0; rg<4; rg++){
      int grow = rbase + rg;
      if (grow < M){
        float dv = dinv[grow];
        #pragma unroll
        for (int ct=0; ct<8; ct++)
          H1B[(size_t)grow*128 + ct*16 + l16] = f2b(dv * acc[rt][ct][rg]);
      }
    }
  }
}

// ---------------- agg1: wave/node gather, 4 edge-groups x 16 lanes x 16B ----------------

__device__ inline void acc8(float* a, uint4 u){
  a[0]+=b2f_lo(u.x); a[1]+=b2f_hi(u.x); a[2]+=b2f_lo(u.y); a[3]+=b2f_hi(u.y);
  a[4]+=b2f_lo(u.z); a[5]+=b2f_hi(u.z); a[6]+=b2f_lo(u.w); a[7]+=b2f_hi(u.w);
}

__global__ __launch_bounds__(256)
void agg1_kernel(const unsigned short* __restrict__ H1B, const int* __restrict__ rowptr,
                 const int* __restrict__ col, const float* __restrict__ dinv,
                 const float* __restrict__ b1, unsigned int* __restrict__ R1B, int N){
  int node = blockIdx.x * 4 + (threadIdx.x >> 6);
  int lane = threadIdx.x & 63;
  int g   = lane >> 4;    // edge sub-group 0..3
  int l16 = lane & 15;    // 16B chunk within the 256B row
  if (node >= N) return;
  int s = rowptr[node], e = rowptr[node+1];
  float a[8];
  #pragma unroll
  for (int k=0;k<8;k++) a[k]=0.f;
  const char* hbase = (const char*)H1B + l16*16;
  int j = s;
  for (; j+15 < e; j+=16){
    int c0 = col[j+g], c1 = col[j+4+g], c2 = col[j+8+g], c3 = col[j+12+g];
    uint4 u0 = *(const uint4*)(hbase + (((unsigned)c0) << 8));
    uint4 u1 = *(const uint4*)(hbase + (((unsigned)c1) << 8));
    uint4 u2 = *(const uint4*)(hbase + (((unsigned)c2) << 8));
    uint4 u3 = *(const uint4*)(hbase + (((unsigned)c3) << 8));
    acc8(a, u0); acc8(a, u1); acc8(a, u2); acc8(a, u3);
  }
  for (; j+7 < e; j+=8){
    int c0 = col[j+g], c1 = col[j+4+g];
    uint4 u0 = *(const uint4*)(hbase + (((unsigned)c0) << 8));
    uint4 u1 = *(const uint4*)(hbase + (((unsigned)c1) << 8));
    acc8(a, u0); acc8(a, u1);
  }
  {
    int rem = e - j;   // 0..7
    if (g < rem){
      int c0 = col[j+g];
      uint4 u0 = *(const uint4*)(hbase + (((unsigned)c0) << 8));
      acc8(a, u0);
    }
    if (g+4 < rem){
      int c1 = col[j+4+g];
      uint4 u1 = *(const uint4*)(hbase + (((unsigned)c1) << 8));
      acc8(a, u1);
    }
  }
  #pragma unroll
  for (int k=0;k<8;k++){
    a[k] += __shfl_xor(a[k], 16);
    a[k] += __shfl_xor(a[k], 32);
  }
  if (g == 0){
    float dv = dinv[node];
    float4 bl = *(const float4*)(b1 + l16*8);
    float4 bh = *(const float4*)(b1 + l16*8 + 4);
    float f0, f1;
    unsigned int o0, o1, o2, o3;
    f0 = fmaxf(dv*a[0] + bl.x, 0.f); f1 = fmaxf(dv*a[1] + bl.y, 0.f);
    o0 = (unsigned)f2b(f0) | ((unsigned)f2b(f1) << 16);
    f0 = fmaxf(dv*a[2] + bl.z, 0.f); f1 = fmaxf(dv*a[3] + bl.w, 0.f);
    o1 = (unsigned)f2b(f0) | ((unsigned)f2b(f1) << 16);
    f0 = fmaxf(dv*a[4] + bh.x, 0.f); f1 = fmaxf(dv*a[5] + bh.y, 0.f);
    o2 = (unsigned)f2b(f0) | ((unsigned)f2b(f1) << 16);
    f0 = fmaxf(dv*a[6] + bh.z, 0.f); f1 = fmaxf(dv*a[7] + bh.w, 0.f);
    o3 = (unsigned)f2b(f0) | ((unsigned)f2b(f1) << 16);
    *(uint4*)(R1B + (size_t)node*64 + l16*4) = make_uint4(o0, o1, o2, o3);
  }
}

// ---------------- GEMM2: h2b[r] = bf16( dinv[r] * (r1[r] @ W2) ), packed 32B stride ----------------
// padding dwords [5..7] zeroed so agg2's wide 8-dword row loads read zeros.

__global__ __launch_bounds__(256)
void gemm2_kernel(const unsigned int* __restrict__ R1B, const float* __restrict__ W2,
                  const float* __restrict__ dinv, unsigned int* __restrict__ H2B, int M){
  __shared__ float w2s[128*10];
  for (int i = threadIdx.x; i < 128*10; i += blockDim.x) w2s[i] = W2[i];
  __syncthreads();
  int r = blockIdx.x*blockDim.x + threadIdx.x;
  if (r >= M) return;
  float acc[10];
  #pragma unroll
  for (int c=0;c<10;c++) acc[c] = 0.f;
  const unsigned int* row = R1B + (size_t)r*64;
  for (int k=0;k<64;k+=4){
    uint4 u = *(const uint4*)(row + k);
    float f0 = b2f_lo(u.x), f1 = b2f_hi(u.x);
    float f2 = b2f_lo(u.y), f3 = b2f_hi(u.y);
    float f4 = b2f_lo(u.z), f5 = b2f_hi(u.z);
    float f6 = b2f_lo(u.w), f7 = b2f_hi(u.w);
    #pragma unroll
    for (int c=0;c<10;c++){
      acc[c] += f0*w2s[(2*k+0)*10+c] + f1*w2s[(2*k+1)*10+c]
              + f2*w2s[(2*k+2)*10+c] + f3*w2s[(2*k+3)*10+c]
              + f4*w2s[(2*k+4)*10+c] + f5*w2s[(2*k+5)*10+c]
              + f6*w2s[(2*k+6)*10+c] + f7*w2s[(2*k+7)*10+c];
    }
  }
  float dv = dinv[r];
  unsigned int p[5];
  #pragma unroll
  for (int c=0;c<5;c++)
    p[c] = (unsigned)f2b(dv*acc[2*c]) | ((unsigned)f2b(dv*acc[2*c+1]) << 16);
  unsigned int* op = H2B + (size_t)r*8;
  *(uint4*)op = make_uint4(p[0],p[1],p[2],p[3]);
  *(uint4*)(op+4) = make_uint4(p[4],0u,0u,0u);
}

// ---------------- agg2 + bias + log_softmax: 16 lanes/node wide gather ----------------

__global__ __launch_bounds__(256)
void agg2_softmax_kernel(const unsigned int* __restrict__ H2B, const int* __restrict__ rowptr,
                         const int* __restrict__ col, const float* __restrict__ dinv,
                         const float* __restrict__ b2, float* __restrict__ out, int N){
  int tid = threadIdx.x;
  int node = blockIdx.x * 16 + (tid >> 4);
  int l16 = tid & 15;
  int g2 = l16 >> 3;      // edge sub-group 0..1
  int l8 = l16 & 7;       // dword slot within 32B row
  if (node >= N) return;
  int s = rowptr[node], e = rowptr[node+1];
  float aLo = 0.f, aHi = 0.f, bLo = 0.f, bHi = 0.f;
  const unsigned int* hb = H2B + l8;
  int j = s;
  for (; j+3 < e; j += 4){
    unsigned u0 = hb[(size_t)col[j+g2]*8];
    unsigned u1 = hb[(size_t)col[j+2+g2]*8];
    aLo += b2f_lo(u0); aHi += b2f_hi(u0);
    bLo += b2f_lo(u1); bHi += b2f_hi(u1);
  }
  for (; j+1 < e; j += 2){
    unsigned u0 = hb[(size_t)col[j+g2]*8];
    aLo += b2f_lo(u0); aHi += b2f_hi(u0);
  }
  if (j < e && g2 == 0){
    unsigned u0 = hb[(size_t)col[j]*8];
    aLo += b2f_lo(u0); aHi += b2f_hi(u0);
  }
  aLo += bLo; aHi += bHi;
  aLo += __shfl_xor(aLo, 8);
  aHi += __shfl_xor(aHi, 8);
  float dv = dinv[node];
  float2 bb = (l8 < 5) ? *(const float2*)(b2 + 2*l8) : make_float2(0.f, 0.f);
  float c0 = (l8 < 5) ? (dv*aLo + bb.x) : -1e30f;
  float c1 = (l8 < 5) ? (dv*aHi + bb.y) : -1e30f;
  float m = fmaxf(c0, c1);
  m = fmaxf(m, __shfl_xor(m, 1));
  m = fmaxf(m, __shfl_xor(m, 2));
  m = fmaxf(m, __shfl_xor(m, 4));
  float ex = (l8 < 5) ? (expf(c0 - m) + expf(c1 - m)) : 0.f;
  ex += __shfl_xor(ex, 1);
  ex += __shfl_xor(ex, 2);
  ex += __shfl_xor(ex, 4);
  float lg = m + logf(ex);
  if (l8 < 5 && g2 == 0)
    *(float2*)(out + (size_t)node*10 + 2*l8) = make_float2(c0 - lg, c1 - lg);
}

// ---------------- launch ----------------

extern "C" void kernel_launch(void* const* d_in, const int* in_sizes, int n_in,
                              void* d_out, int out_size, void* d_ws, size_t ws_size,
                              hipStream_t stream){
  const float* x    = (const float*)d_in[0];
  const int*   ei   = (const int*)d_in[1];
  const float* W1   = (const float*)d_in[2];
  const float* b1   = (const float*)d_in[3];
  const float* W2   = (const float*)d_in[4];
  const float* b2   = (const float*)d_in[5];
  float* out = (float*)d_out;

  const int N = in_sizes[0] / 256;   // 100000
  const int E = in_sizes[1] / 2;     // 1600000
  const int NNZ = E + N;
  const int* src = ei;
  const int* dst = ei + E;
  const int NB = (N + BKT - 1) >> BKT_BITS;   // 391 buckets
  const int WB = 128;                         // wcvt tail blocks

  char* ws = (char*)d_ws;
  size_t off = 0;
  auto alloc = [&](size_t bytes)->char*{
    char* p = ws + off;
    off = (off + bytes + 255) & ~(size_t)255;
    return p;
  };
  int*   bcnt   = (int*)  alloc((size_t)NBMAX*4);   // zeroed; reservation + final counts
  float* dinv   = (float*)alloc((size_t)N*4);
  int*   rowptr = (int*)  alloc((size_t)(N+1)*4);
  unsigned int* bins = (unsigned int*)alloc((size_t)NB*BSTRIDE*4);
  int*   col    = (int*)  alloc((size_t)NNZ*4);
  unsigned short* w1t = (unsigned short*)alloc((size_t)128*256*2);
  unsigned short* h1b = (unsigned short*)alloc((size_t)N*128*2);
  unsigned int*   r1b = (unsigned int*)  alloc((size_t)N*64*4);
  unsigned int*   h2b = (unsigned int*)  alloc((size_t)N*8*4);
  (void)ws_size;

  hipMemsetAsync(bcnt, 0, (size_t)NBMAX*4, stream);

  const int NCB = (E + EB - 1) / EB;   // 782 bin blocks

  binC<<<NCB, 256, 0, stream>>>(src, dst, bcnt, bins, E, NB);
  bfill_all<<<NB + WB, 256, 0, stream>>>(bins, bcnt, rowptr, dinv, col, W1, w1t, N, NB);

  gemm1_mfma<<<(N+255)/256, 512, 0, stream>>>(x, w1t, dinv, h1b, N);
  agg1_kernel<<<(N+3)/4, 256, 0, stream>>>(h1b, rowptr, col, dinv, b1, r1b, N);
  gemm2_kernel<<<(N+BLK-1)/BLK, BLK, 0, stream>>>(r1b, W2, dinv, h2b, N);
  agg2_softmax_kernel<<<(N+15)/16, BLK, 0, stream>>>(h2b, rowptr, col, dinv, b2, out, N);
}

// Round 11
// 316.116 us; speedup vs baseline: 1.6429x; 1.0194x over previous
//
#include <hip/hip_runtime.h>
#include <math.h>

#define BLK 256
// bucketed CSR build: 256 dst-nodes per bucket
#define BKT_BITS 8
#define BKT (1<<BKT_BITS)
#define NBMAX 512
#define EB 2048       // edges per bin-block
#define BSTRIDE 8192  // per-bucket slot stride in bins (mean fill 4092, 64-sigma safe)

typedef __attribute__((ext_vector_type(8))) short bf16x8;
typedef __attribute__((ext_vector_type(4))) float f32x4;

__device__ inline unsigned short f2b(float f){
  union { float f; unsigned int u; } v; v.f = f;
  unsigned int u = v.u;
  return (unsigned short)((u + 0x7FFF + ((u >> 16) & 1)) >> 16);
}
__device__ inline float b2f_lo(unsigned int u){
  union { unsigned int u; float f; } v; v.u = u << 16; return v.f;
}
__device__ inline float b2f_hi(unsigned int u){
  union { unsigned int u; float f; } v; v.u = u & 0xFFFF0000u; return v.f;
}
// packed 2xbf16 convert (RNE, same rounding as f2b) — 1 instr per 2 floats
__device__ inline unsigned pkbf(float lo, float hi){
  unsigned r;
  asm("v_cvt_pk_bf16_f32 %0, %1, %2" : "=v"(r) : "v"(lo), "v"(hi));
  return r;
}

// ---------------- K1: binC (edge bucketing) || W1 transpose/cvt ----------------
// Independent chains co-scheduled in one kernel: blocks [0,NCB) bucket edges,
// blocks [NCB, NCB+WB) convert W1 -> W1T. Both need only raw inputs.

__global__ __launch_bounds__(256)
void binc_wcvt(const int* __restrict__ src, const int* __restrict__ dst,
               int* __restrict__ bcnt, unsigned int* __restrict__ bins,
               const float* __restrict__ W1, unsigned short* __restrict__ W1T,
               int E, int NCB){
  __shared__ int lh[NBMAX];
  __shared__ int lofs[NBMAX];
  __shared__ int lcur[NBMAX];
  __shared__ int gres[NBMAX];
  __shared__ int sscan[256];
  __shared__ __attribute__((aligned(16))) int2 buf[EB];
  int b = blockIdx.x;
  if (b >= NCB){   // W1 transpose+cvt
    int t2 = (b - NCB)*256 + threadIdx.x;
    if (t2 < 256*128){
      int k = t2 >> 7, n = t2 & 127;
      W1T[n*256 + k] = f2b(W1[t2]);
    }
    return;
  }
  int t = threadIdx.x;
  lh[t] = 0; lh[t+256] = 0;
  __syncthreads();
  int base = b*EB;
  // histogram: int4 edge loads (E % 4 == 0)
  #pragma unroll
  for (int k=0;k<EB/1024;k++){
    int idx = base + (k*256 + t)*4;
    if (idx < E){
      int4 d = *(const int4*)(dst + idx);
      atomicAdd(&lh[d.x>>BKT_BITS],1);
      atomicAdd(&lh[d.y>>BKT_BITS],1);
      atomicAdd(&lh[d.z>>BKT_BITS],1);
      atomicAdd(&lh[d.w>>BKT_BITS],1);
    }
  }
  __syncthreads();
  // exclusive scan of lh[0..512) (2 entries/thread)
  int i0 = 2*t, i1 = 2*t+1;
  int v0 = lh[i0], v1 = lh[i1];
  int tsum = v0+v1;
  sscan[t] = tsum; __syncthreads();
  for (int off=1; off<256; off<<=1){
    int v = (t>=off)? sscan[t-off]:0;
    __syncthreads();
    sscan[t]+=v;
    __syncthreads();
  }
  int run = sscan[t]-tsum;
  lofs[i0] = run;      lofs[i1] = run+v0;
  lcur[i0] = run;      lcur[i1] = run+v0;
  for (int i=t;i<NBMAX;i+=256)
    gres[i] = lh[i] ? (i*BSTRIDE + atomicAdd(&bcnt[i], lh[i])) : 0;
  __syncthreads();
  // scatter into LDS buf grouped by bucket
  #pragma unroll
  for (int k=0;k<EB/1024;k++){
    int idx = base + (k*256 + t)*4;
    if (idx < E){
      int4 s4 = *(const int4*)(src + idx);
      int4 d4 = *(const int4*)(dst + idx);
      int p;
      p = atomicAdd(&lcur[d4.x>>BKT_BITS],1); buf[p] = make_int2(s4.x,d4.x);
      p = atomicAdd(&lcur[d4.y>>BKT_BITS],1); buf[p] = make_int2(s4.y,d4.y);
      p = atomicAdd(&lcur[d4.z>>BKT_BITS],1); buf[p] = make_int2(s4.z,d4.z);
      p = atomicAdd(&lcur[d4.w>>BKT_BITS],1); buf[p] = make_int2(s4.w,d4.w);
    }
  }
  __syncthreads();
  // dense packed writeout: src<<8 | dst&255
  int total = E - base; if (total > EB) total = EB;
  for (int i=t; i<total; i+=256){
    int2 pr = buf[i];
    int bb = pr.y>>BKT_BITS;
    bins[gres[bb] + (i - lofs[bb])] = ((unsigned)pr.x << BKT_BITS) | (unsigned)(pr.y & (BKT-1));
  }
}

// ---------------- K2: bfill (CSR finalize) || gemm1 v4 (MFMA) ----------------
// blocks [0,NB): bfill @512t (needs bins from K1); blocks [NB,NB+GB): gemm1
// (needs w1t from K1). LDS is a 64KB union. Latency-bound CSR atomics overlap
// gemm1's MFMA on the same CUs.

__global__ __launch_bounds__(512)
void bfill_gemm1(const unsigned int* __restrict__ bins, const int* __restrict__ bcnt,
                 int* __restrict__ rowptr, float* __restrict__ dinv, int* __restrict__ col,
                 const float* __restrict__ X, const unsigned short* __restrict__ W1T,
                 unsigned short* __restrict__ H1B, int N, int NB){
  __shared__ __attribute__((aligned(16))) char smem[64*512*2];   // 64KB union
  const int b = blockIdx.x;
  const int t = threadIdx.x;

  if (b < NB){
    // ---- bfill branch (512 threads) ----
    int* dcnt  = (int*)smem;
    int* rp    = dcnt + 256;
    int* cur   = rp + 256;
    int* sscan = cur + 256;
    int* sboff = sscan + 256;
    if (t == 0) *sboff = 0;
    if (t < 256) dcnt[t] = 0;
    __syncthreads();
    int partial = 0;
    for (int j=t; j<b; j+=512) partial += bcnt[j];
    if (partial) atomicAdd(sboff, partial);
    __syncthreads();
    int s = *sboff, cnt = bcnt[b];
    const unsigned int* mybins = bins + (size_t)b*BSTRIDE;
    for (int i=t;i<cnt;i+=512) atomicAdd(&dcnt[mybins[i] & (BKT-1)], 1);
    __syncthreads();
    int base = b<<BKT_BITS;
    int node = base + t;
    int d0 = 0, n0 = 0;
    if (t < 256){
      d0 = dcnt[t];
      n0 = (node < N) ? d0+1 : 0;
      sscan[t] = n0;
    }
    __syncthreads();
    for (int off=1; off<256; off<<=1){
      int v = 0;
      if (t < 256 && t >= off) v = sscan[t-off];
      __syncthreads();
      if (t < 256) sscan[t] += v;
      __syncthreads();
    }
    if (t < 256){
      int run = sscan[t]-n0;
      int rp0 = s + base + run;   // prior buckets: s edges + base self-loops
      rp[t] = rp0; cur[t] = 0;
      if (node < N){
        rowptr[node] = rp0;
        dinv[node] = rsqrtf((float)(d0+1));
        col[rp0 + d0] = node;               // self-loop last (slot disjoint from fill)
        if (node == N-1) rowptr[N] = rp0 + d0 + 1;
      }
    }
    __syncthreads();
    for (int i=t;i<cnt;i+=512){
      unsigned pk = mybins[i];
      int ln = pk & (BKT-1);
      int slot = atomicAdd(&cur[ln], 1);
      col[rp[ln] + slot] = (int)(pk >> BKT_BITS);
    }
    return;
  }

  // ---- gemm1 v4 branch (512 threads, 8 waves x 32 rows) ----
  unsigned short* wsh = (unsigned short*)smem;   // 64 frags * 512 shorts
  const int bid = b - NB;
  const int wave = t >> 6, lane = t & 63;
  const int quad = lane >> 4, l16 = lane & 15;
  const int M = N;

  #pragma unroll
  for (int f0=0; f0<64; f0+=8){
    int f = f0 + wave;
    int ct = f >> 3, ts = f & 7;
    uint4 v = *(const uint4*)(W1T + (ct*16 + l16)*256 + ts*32 + quad*8);
    *(uint4*)(wsh + f*512 + lane*8) = v;
  }
  __syncthreads();

  const int row0 = bid * 256 + wave * 32;
  int rA = row0 + l16;
  int rB = rA + 16;
  int rAc = (rA < M) ? rA : (M-1);
  int rBc = (rB < M) ? rB : (M-1);
  const float* xA = X + (size_t)rAc*256 + quad*8;
  const float* xB = X + (size_t)rBc*256 + quad*8;

  f32x4 acc[2][8];
  #pragma unroll
  for (int i=0;i<2;i++)
    #pragma unroll
    for (int j=0;j<8;j++) acc[i][j] = (f32x4){0.f,0.f,0.f,0.f};

  float4 pf[2][4];
  #pragma unroll
  for (int s=0;s<2;s++){
    pf[s][0] = *(const float4*)(xA + s*32);
    pf[s][1] = *(const float4*)(xA + s*32 + 4);
    pf[s][2] = *(const float4*)(xB + s*32);
    pf[s][3] = *(const float4*)(xB + s*32 + 4);
  }

  #pragma unroll
  for (int tt=0; tt<8; tt++){
    const int cur2 = tt & 1;
    union { bf16x8 v; unsigned u[4]; } fa, fb;
    fa.u[0] = pkbf(pf[cur2][0].x, pf[cur2][0].y);
    fa.u[1] = pkbf(pf[cur2][0].z, pf[cur2][0].w);
    fa.u[2] = pkbf(pf[cur2][1].x, pf[cur2][1].y);
    fa.u[3] = pkbf(pf[cur2][1].z, pf[cur2][1].w);
    fb.u[0] = pkbf(pf[cur2][2].x, pf[cur2][2].y);
    fb.u[1] = pkbf(pf[cur2][2].z, pf[cur2][2].w);
    fb.u[2] = pkbf(pf[cur2][3].x, pf[cur2][3].y);
    fb.u[3] = pkbf(pf[cur2][3].z, pf[cur2][3].w);
    if (tt < 6){
      pf[cur2][0] = *(const float4*)(xA + (tt+2)*32);
      pf[cur2][1] = *(const float4*)(xA + (tt+2)*32 + 4);
      pf[cur2][2] = *(const float4*)(xB + (tt+2)*32);
      pf[cur2][3] = *(const float4*)(xB + (tt+2)*32 + 4);
    }
    #pragma unroll
    for (int ct=0; ct<8; ct++){
      bf16x8 bf = *(const bf16x8*)(wsh + (ct*8 + tt)*512 + lane*8);
      acc[0][ct] = __builtin_amdgcn_mfma_f32_16x16x32_bf16(fa.v, bf, acc[0][ct], 0, 0, 0);
      acc[1][ct] = __builtin_amdgcn_mfma_f32_16x16x32_bf16(fb.v, bf, acc[1][ct], 0, 0, 0);
    }
  }

  #pragma unroll
  for (int rt=0; rt<2; rt++){
    int rbase = row0 + rt*16 + quad*4;
    #pragma unroll
    for (int rg=0; rg<4; rg++){
      int grow = rbase + rg;
      if (grow < M){
        float dv = dinv[grow];
        #pragma unroll
        for (int ct=0; ct<8; ct++)
          H1B[(size_t)grow*128 + ct*16 + l16] = f2b(dv * acc[rt][ct][rg]);
      }
    }
  }
}

// ---------------- agg1: wave/node gather, 4 edge-groups x 16 lanes x 16B ----------------

__device__ inline void acc8(float* a, uint4 u){
  a[0]+=b2f_lo(u.x); a[1]+=b2f_hi(u.x); a[2]+=b2f_lo(u.y); a[3]+=b2f_hi(u.y);
  a[4]+=b2f_lo(u.z); a[5]+=b2f_hi(u.z); a[6]+=b2f_lo(u.w); a[7]+=b2f_hi(u.w);
}

__global__ __launch_bounds__(256)
void agg1_kernel(const unsigned short* __restrict__ H1B, const int* __restrict__ rowptr,
                 const int* __restrict__ col, const float* __restrict__ dinv,
                 const float* __restrict__ b1, unsigned int* __restrict__ R1B, int N){
  int node = blockIdx.x * 4 + (threadIdx.x >> 6);
  int lane = threadIdx.x & 63;
  int g   = lane >> 4;    // edge sub-group 0..3
  int l16 = lane & 15;    // 16B chunk within the 256B row
  if (node >= N) return;
  int s = rowptr[node], e = rowptr[node+1];
  float a[8];
  #pragma unroll
  for (int k=0;k<8;k++) a[k]=0.f;
  const char* hbase = (const char*)H1B + l16*16;
  int j = s;
  for (; j+15 < e; j+=16){
    int c0 = col[j+g], c1 = col[j+4+g], c2 = col[j+8+g], c3 = col[j+12+g];
    uint4 u0 = *(const uint4*)(hbase + (((unsigned)c0) << 8));
    uint4 u1 = *(const uint4*)(hbase + (((unsigned)c1) << 8));
    uint4 u2 = *(const uint4*)(hbase + (((unsigned)c2) << 8));
    uint4 u3 = *(const uint4*)(hbase + (((unsigned)c3) << 8));
    acc8(a, u0); acc8(a, u1); acc8(a, u2); acc8(a, u3);
  }
  for (; j+7 < e; j+=8){
    int c0 = col[j+g], c1 = col[j+4+g];
    uint4 u0 = *(const uint4*)(hbase + (((unsigned)c0) << 8));
    uint4 u1 = *(const uint4*)(hbase + (((unsigned)c1) << 8));
    acc8(a, u0); acc8(a, u1);
  }
  {
    int rem = e - j;   // 0..7
    if (g < rem){
      int c0 = col[j+g];
      uint4 u0 = *(const uint4*)(hbase + (((unsigned)c0) << 8));
      acc8(a, u0);
    }
    if (g+4 < rem){
      int c1 = col[j+4+g];
      uint4 u1 = *(const uint4*)(hbase + (((unsigned)c1) << 8));
      acc8(a, u1);
    }
  }
  #pragma unroll
  for (int k=0;k<8;k++){
    a[k] += __shfl_xor(a[k], 16);
    a[k] += __shfl_xor(a[k], 32);
  }
  if (g == 0){
    float dv = dinv[node];
    float4 bl = *(const float4*)(b1 + l16*8);
    float4 bh = *(const float4*)(b1 + l16*8 + 4);
    float f0, f1;
    unsigned int o0, o1, o2, o3;
    f0 = fmaxf(dv*a[0] + bl.x, 0.f); f1 = fmaxf(dv*a[1] + bl.y, 0.f);
    o0 = (unsigned)f2b(f0) | ((unsigned)f2b(f1) << 16);
    f0 = fmaxf(dv*a[2] + bl.z, 0.f); f1 = fmaxf(dv*a[3] + bl.w, 0.f);
    o1 = (unsigned)f2b(f0) | ((unsigned)f2b(f1) << 16);
    f0 = fmaxf(dv*a[4] + bh.x, 0.f); f1 = fmaxf(dv*a[5] + bh.y, 0.f);
    o2 = (unsigned)f2b(f0) | ((unsigned)f2b(f1) << 16);
    f0 = fmaxf(dv*a[6] + bh.z, 0.f); f1 = fmaxf(dv*a[7] + bh.w, 0.f);
    o3 = (unsigned)f2b(f0) | ((unsigned)f2b(f1) << 16);
    *(uint4*)(R1B + (size_t)node*64 + l16*4) = make_uint4(o0, o1, o2, o3);
  }
}

// ---------------- GEMM2: h2b[r] = bf16( dinv[r] * (r1[r] @ W2) ), packed 32B stride ----------------
// padding dwords [5..7] zeroed so agg2's wide 8-dword row loads read zeros.

__global__ __launch_bounds__(256)
void gemm2_kernel(const unsigned int* __restrict__ R1B, const float* __restrict__ W2,
                  const float* __restrict__ dinv, unsigned int* __restrict__ H2B, int M){
  __shared__ float w2s[128*10];
  for (int i = threadIdx.x; i < 128*10; i += blockDim.x) w2s[i] = W2[i];
  __syncthreads();
  int r = blockIdx.x*blockDim.x + threadIdx.x;
  if (r >= M) return;
  float acc[10];
  #pragma unroll
  for (int c=0;c<10;c++) acc[c] = 0.f;
  const unsigned int* row = R1B + (size_t)r*64;
  for (int k=0;k<64;k+=4){
    uint4 u = *(const uint4*)(row + k);
    float f0 = b2f_lo(u.x), f1 = b2f_hi(u.x);
    float f2 = b2f_lo(u.y), f3 = b2f_hi(u.y);
    float f4 = b2f_lo(u.z), f5 = b2f_hi(u.z);
    float f6 = b2f_lo(u.w), f7 = b2f_hi(u.w);
    #pragma unroll
    for (int c=0;c<10;c++){
      acc[c] += f0*w2s[(2*k+0)*10+c] + f1*w2s[(2*k+1)*10+c]
              + f2*w2s[(2*k+2)*10+c] + f3*w2s[(2*k+3)*10+c]
              + f4*w2s[(2*k+4)*10+c] + f5*w2s[(2*k+5)*10+c]
              + f6*w2s[(2*k+6)*10+c] + f7*w2s[(2*k+7)*10+c];
    }
  }
  float dv = dinv[r];
  unsigned int p[5];
  #pragma unroll
  for (int c=0;c<5;c++)
    p[c] = (unsigned)f2b(dv*acc[2*c]) | ((unsigned)f2b(dv*acc[2*c+1]) << 16);
  unsigned int* op = H2B + (size_t)r*8;
  *(uint4*)op = make_uint4(p[0],p[1],p[2],p[3]);
  *(uint4*)(op+4) = make_uint4(p[4],0u,0u,0u);
}

// ---------------- agg2 + bias + log_softmax: 16 lanes/node wide gather ----------------

__global__ __launch_bounds__(256)
void agg2_softmax_kernel(const unsigned int* __restrict__ H2B, const int* __restrict__ rowptr,
                         const int* __restrict__ col, const float* __restrict__ dinv,
                         const float* __restrict__ b2, float* __restrict__ out, int N){
  int tid = threadIdx.x;
  int node = blockIdx.x * 16 + (tid >> 4);
  int l16 = tid & 15;
  int g2 = l16 >> 3;      // edge sub-group 0..1
  int l8 = l16 & 7;       // dword slot within 32B row
  if (node >= N) return;
  int s = rowptr[node], e = rowptr[node+1];
  float aLo = 0.f, aHi = 0.f, bLo = 0.f, bHi = 0.f;
  const unsigned int* hb = H2B + l8;
  int j = s;
  for (; j+3 < e; j += 4){
    unsigned u0 = hb[(size_t)col[j+g2]*8];
    unsigned u1 = hb[(size_t)col[j+2+g2]*8];
    aLo += b2f_lo(u0); aHi += b2f_hi(u0);
    bLo += b2f_lo(u1); bHi += b2f_hi(u1);
  }
  for (; j+1 < e; j += 2){
    unsigned u0 = hb[(size_t)col[j+g2]*8];
    aLo += b2f_lo(u0); aHi += b2f_hi(u0);
  }
  if (j < e && g2 == 0){
    unsigned u0 = hb[(size_t)col[j]*8];
    aLo += b2f_lo(u0); aHi += b2f_hi(u0);
  }
  aLo += bLo; aHi += bHi;
  aLo += __shfl_xor(aLo, 8);
  aHi += __shfl_xor(aHi, 8);
  float dv = dinv[node];
  float2 bb = (l8 < 5) ? *(const float2*)(b2 + 2*l8) : make_float2(0.f, 0.f);
  float c0 = (l8 < 5) ? (dv*aLo + bb.x) : -1e30f;
  float c1 = (l8 < 5) ? (dv*aHi + bb.y) : -1e30f;
  float m = fmaxf(c0, c1);
  m = fmaxf(m, __shfl_xor(m, 1));
  m = fmaxf(m, __shfl_xor(m, 2));
  m = fmaxf(m, __shfl_xor(m, 4));
  float ex = (l8 < 5) ? (expf(c0 - m) + expf(c1 - m)) : 0.f;
  ex += __shfl_xor(ex, 1);
  ex += __shfl_xor(ex, 2);
  ex += __shfl_xor(ex, 4);
  float lg = m + logf(ex);
  if (l8 < 5 && g2 == 0)
    *(float2*)(out + (size_t)node*10 + 2*l8) = make_float2(c0 - lg, c1 - lg);
}

// ---------------- launch ----------------

extern "C" void kernel_launch(void* const* d_in, const int* in_sizes, int n_in,
                              void* d_out, int out_size, void* d_ws, size_t ws_size,
                              hipStream_t stream){
  const float* x    = (const float*)d_in[0];
  const int*   ei   = (const int*)d_in[1];
  const float* W1   = (const float*)d_in[2];
  const float* b1   = (const float*)d_in[3];
  const float* W2   = (const float*)d_in[4];
  const float* b2   = (const float*)d_in[5];
  float* out = (float*)d_out;

  const int N = in_sizes[0] / 256;   // 100000
  const int E = in_sizes[1] / 2;     // 1600000
  const int NNZ = E + N;
  const int* src = ei;
  const int* dst = ei + E;
  const int NB = (N + BKT - 1) >> BKT_BITS;   // 391 buckets
  const int WB = 128;                         // wcvt tail blocks
  const int GB = (N + 255) / 256;             // 391 gemm1 blocks

  char* ws = (char*)d_ws;
  size_t off = 0;
  auto alloc = [&](size_t bytes)->char*{
    char* p = ws + off;
    off = (off + bytes + 255) & ~(size_t)255;
    return p;
  };
  int*   bcnt   = (int*)  alloc((size_t)NBMAX*4);   // zeroed; reservation + final counts
  float* dinv   = (float*)alloc((size_t)N*4);
  int*   rowptr = (int*)  alloc((size_t)(N+1)*4);
  unsigned int* bins = (unsigned int*)alloc((size_t)NB*BSTRIDE*4);
  int*   col    = (int*)  alloc((size_t)NNZ*4);
  unsigned short* w1t = (unsigned short*)alloc((size_t)128*256*2);
  unsigned short* h1b = (unsigned short*)alloc((size_t)N*128*2);
  unsigned int*   r1b = (unsigned int*)  alloc((size_t)N*64*4);
  unsigned int*   h2b = (unsigned int*)  alloc((size_t)N*8*4);
  (void)ws_size;

  hipMemsetAsync(bcnt, 0, (size_t)NBMAX*4, stream);

  const int NCB = (E + EB - 1) / EB;   // 782 bin blocks

  binc_wcvt<<<NCB + WB, 256, 0, stream>>>(src, dst, bcnt, bins, W1, w1t, E, NCB);
  bfill_gemm1<<<NB + GB, 512, 0, stream>>>(bins, bcnt, rowptr, dinv, col, x, w1t, h1b, N, NB);

  agg1_kernel<<<(N+3)/4, 256, 0, stream>>>(h1b, rowptr, col, dinv, b1, r1b, N);
  gemm2_kernel<<<(N+BLK-1)/BLK, BLK, 0, stream>>>(r1b, W2, dinv, h2b, N);
  agg2_softmax_kernel<<<(N+15)/16, BLK, 0, stream>>>(h2b, rowptr, col, dinv, b2, out, N);
}